// Round 1
// baseline (1033.798 us; speedup 1.0000x reference)
//
#include <hip/hip_runtime.h>
#include <cmath>

#define NN   50000
#define DIMC 128
#define HC   8
#define HDC  16
#define DC   16

// ---------------- LayerNorm #1: x = LN(feat)*g1 + b1 ----------------
__global__ __launch_bounds__(256) void k_ln1(const float* __restrict__ in,
                                             const float* __restrict__ g,
                                             const float* __restrict__ b,
                                             float* __restrict__ out) {
    int wid  = threadIdx.x >> 6;
    int lane = threadIdx.x & 63;
    int row  = blockIdx.x * 4 + wid;
    if (row >= NN) return;
    const float* rp = in + (size_t)row * DIMC;
    float2 v = *(const float2*)(rp + lane * 2);
    float s = v.x + v.y;
#pragma unroll
    for (int off = 32; off; off >>= 1) s += __shfl_xor(s, off);
    float mu = s * (1.0f / DIMC);
    float dx = v.x - mu, dy = v.y - mu;
    float sq = dx * dx + dy * dy;
#pragma unroll
    for (int off = 32; off; off >>= 1) sq += __shfl_xor(sq, off);
    float var  = sq * (1.0f / DIMC);
    float rstd = 1.0f / sqrtf(var + 1e-5f);
    float2 gv = *(const float2*)(g + lane * 2);
    float2 bv = *(const float2*)(b + lane * 2);
    float2 o;
    o.x = dx * rstd * gv.x + bv.x;
    o.y = dy * rstd * gv.y + bv.y;
    *(float2*)(out + (size_t)row * DIMC + lane * 2) = o;
}

// ---------------- 3x GEMM: C = x @ W (N x 128 @ 128 x 128) ----------------
// block: 128 threads, tile 64 rows x 128 cols, k-chunks of 32.
__global__ __launch_bounds__(128) void k_gemm3(const float* __restrict__ A,
                                               const float* __restrict__ B0,
                                               const float* __restrict__ B1,
                                               const float* __restrict__ B2,
                                               float* __restrict__ C0,
                                               float* __restrict__ C1,
                                               float* __restrict__ C2) {
    const float* B = (blockIdx.y == 0) ? B0 : (blockIdx.y == 1 ? B1 : B2);
    float*       C = (blockIdx.y == 0) ? C0 : (blockIdx.y == 1 ? C1 : C2);
    __shared__ __align__(16) float As[32][68];   // [k][row], padded
    __shared__ __align__(16) float Bs[32][128];  // [k][col]
    int t  = threadIdx.x;
    int tr = t >> 4, tc = t & 15;        // tr:0..7 rows tr*8.., tc:0..15 cols tc*8..
    int r0 = blockIdx.x * 64;

    float acc[8][8];
#pragma unroll
    for (int i = 0; i < 8; i++)
#pragma unroll
        for (int j = 0; j < 8; j++) acc[i][j] = 0.0f;

    for (int kc = 0; kc < 4; kc++) {
#pragma unroll
        for (int i = 0; i < 16; i++) {           // stage A: 64x32 transposed
            int e = t + i * 128;
            int row = e >> 5, kk = e & 31;
            int gr = r0 + row;
            float v = (gr < NN) ? A[(size_t)gr * DIMC + kc * 32 + kk] : 0.0f;
            As[kk][row] = v;
        }
#pragma unroll
        for (int i = 0; i < 32; i++) {           // stage B: 32x128
            int e = t + i * 128;
            int kk = e >> 7, c = e & 127;
            Bs[kk][c] = B[(size_t)(kc * 32 + kk) * DIMC + c];
        }
        __syncthreads();
#pragma unroll 4
        for (int kk = 0; kk < 32; kk++) {
            float4 a0 = *(const float4*)&As[kk][tr * 8];
            float4 a1 = *(const float4*)&As[kk][tr * 8 + 4];
            float4 b0 = *(const float4*)&Bs[kk][tc * 8];
            float4 b1 = *(const float4*)&Bs[kk][tc * 8 + 4];
            float av[8] = {a0.x, a0.y, a0.z, a0.w, a1.x, a1.y, a1.z, a1.w};
            float bv[8] = {b0.x, b0.y, b0.z, b0.w, b1.x, b1.y, b1.z, b1.w};
#pragma unroll
            for (int i = 0; i < 8; i++)
#pragma unroll
                for (int j = 0; j < 8; j++) acc[i][j] = fmaf(av[i], bv[j], acc[i][j]);
        }
        __syncthreads();
    }
#pragma unroll
    for (int i = 0; i < 8; i++) {
        int gr = r0 + tr * 8 + i;
        if (gr < NN) {
            float4 o0 = {acc[i][0], acc[i][1], acc[i][2], acc[i][3]};
            float4 o1 = {acc[i][4], acc[i][5], acc[i][6], acc[i][7]};
            *(float4*)&C[(size_t)gr * DIMC + tc * 8]     = o0;
            *(float4*)&C[(size_t)gr * DIMC + tc * 8 + 4] = o1;
        }
    }
}

// ---------------- scores -> softmax -> top-5 threshold -> a_n ----------------
// one thread per (n, h)
__global__ __launch_bounds__(256) void k_score(const float* __restrict__ fh,
                                               const float* __restrict__ ft,
                                               const float* __restrict__ attn,
                                               const int* __restrict__ src,
                                               float* __restrict__ an) {
    int idx = blockIdx.x * 256 + threadIdx.x;
    if (idx >= NN * HC) return;
    int n = idx >> 3, h = idx & 7;

    float ftv[16], atv[16];
    const float* ftp = ft + (size_t)n * DIMC + h * HDC;
    const float* atp = attn + h * HDC;
#pragma unroll
    for (int q = 0; q < 4; q++) {
        float4 a = *(const float4*)(ftp + q * 4);
        float4 b = *(const float4*)(atp + q * 4);
        ftv[q * 4 + 0] = a.x; ftv[q * 4 + 1] = a.y; ftv[q * 4 + 2] = a.z; ftv[q * 4 + 3] = a.w;
        atv[q * 4 + 0] = b.x; atv[q * 4 + 1] = b.y; atv[q * 4 + 2] = b.z; atv[q * 4 + 3] = b.w;
    }
    const int* sp = src + (size_t)n * DC;
    const float scale = logf(17.0f) / 16.0f;   // log(D+1)/HD
    float sc[16];
#pragma unroll
    for (int d = 0; d < 16; d++) {
        int r = sp[d];
        const float* fp = fh + (size_t)r * DIMC + h * HDC;
        float s = 0.0f;
#pragma unroll
        for (int q = 0; q < 4; q++) {
            float4 v = *(const float4*)(fp + q * 4);
            float e;
            e = v.x + ftv[q * 4 + 0]; e = e > 0.0f ? e : 0.2f * e; s = fmaf(atv[q * 4 + 0], e, s);
            e = v.y + ftv[q * 4 + 1]; e = e > 0.0f ? e : 0.2f * e; s = fmaf(atv[q * 4 + 1], e, s);
            e = v.z + ftv[q * 4 + 2]; e = e > 0.0f ? e : 0.2f * e; s = fmaf(atv[q * 4 + 2], e, s);
            e = v.w + ftv[q * 4 + 3]; e = e > 0.0f ? e : 0.2f * e; s = fmaf(atv[q * 4 + 3], e, s);
        }
        sc[d] = s * scale;
    }
    // softmax over d
    float m = sc[0];
#pragma unroll
    for (int d = 1; d < 16; d++) m = fmaxf(m, sc[d]);
    float p[16]; float sum = 0.0f;
#pragma unroll
    for (int d = 0; d < 16; d++) { p[d] = expf(sc[d] - m); sum += p[d]; }
    float a[16];
#pragma unroll
    for (int d = 0; d < 16; d++) a[d] = p[d] / sum;
    // 5th-largest (counting multiplicity) — matches jnp.top_k semantics
    float tmp[16];
#pragma unroll
    for (int d = 0; d < 16; d++) tmp[d] = a[d];
    float thr = 0.0f;
#pragma unroll
    for (int k = 0; k < 5; k++) {
        float vm = tmp[0];
#pragma unroll
        for (int d = 1; d < 16; d++) vm = fmaxf(vm, tmp[d]);
        thr = vm;
        bool rem = false;
#pragma unroll
        for (int d = 0; d < 16; d++) {
            if (!rem && tmp[d] == vm) { tmp[d] = -1.0f; rem = true; }
        }
    }
    float tsum = 0.0f;
#pragma unroll
    for (int d = 0; d < 16; d++) if (a[d] >= thr) tsum += a[d];
    float* op = an + (size_t)n * DIMC + h * DC;
#pragma unroll
    for (int d = 0; d < 16; d++) op[d] = (a[d] >= thr) ? a[d] / tsum : 0.0f;
}

// ---------------- one propagation hop ----------------
// h_out[n,h,f] = 0.9 * sum_d a_n[n,h,d]*h_in[src[n,d],h,f] + 0.1*fe[n,h,f]
__global__ __launch_bounds__(256) void k_hop(const float* __restrict__ hin,
                                             const float* __restrict__ fe,
                                             const float* __restrict__ an,
                                             const int* __restrict__ src,
                                             float* __restrict__ hout) {
    __shared__ float s_an[2][128];
    __shared__ int   s_src[2][16];
    int t  = threadIdx.x;
    int n0 = blockIdx.x * 2;
    {
        int ln = t >> 7, c = t & 127;
        s_an[ln][c] = an[(size_t)(n0 + ln) * DIMC + c];
        if (t < 32) s_src[t >> 4][t & 15] = src[(size_t)(n0 + (t >> 4)) * DC + (t & 15)];
    }
    __syncthreads();
    int ln  = t >> 7;
    int loc = t & 127;          // hh*16 + f
    int hh  = loc >> 4;
    size_t n = n0 + ln;
    float acc = 0.0f;
#pragma unroll
    for (int d = 0; d < 16; d++) {
        float w = s_an[ln][hh * 16 + d];
        if (w != 0.0f) {                       // uniform per 16-lane group: skips the cacheline fetch
            int r = s_src[ln][d];
            acc = fmaf(w, hin[(size_t)r * DIMC + loc], acc);
        }
    }
    hout[n * DIMC + loc] = 0.9f * acc + 0.1f * fe[n * DIMC + loc];
}

// ---------------- rst = h + feat; y = LN2(rst); out = relu(y@W1+b1)@W2+b2 + rst ----
// block: 256 threads, 64 rows; 16 column-chunks of 32 over the 512 hidden dim.
__global__ __launch_bounds__(256) void k_final(const float* __restrict__ hfin,
                                               const float* __restrict__ feat,
                                               const float* __restrict__ g2,
                                               const float* __restrict__ b2,
                                               const float* __restrict__ W1,
                                               const float* __restrict__ bf1,
                                               const float* __restrict__ W2,
                                               const float* __restrict__ bf2,
                                               float* __restrict__ out) {
    __shared__ __align__(16) float y_t[128][64];   // [k][row] 32KB
    __shared__ __align__(16) float wbuf[4096];     // 16KB: W1 chunk [128][32] / W2 chunk [32][128]
    __shared__ __align__(16) float ts[64][36];     // t chunk [row][c] 9KB (stride 36 to spread banks)
    int t  = threadIdx.x;
    int r0 = blockIdx.x * 64;

    // ---- rst + LN2 into y_t (transposed) ----
    {
        int row = t >> 2, part = t & 3;
        int gr = r0 + row;
        float vals[32];
        if (gr < NN) {
            const float* hp = hfin + (size_t)gr * DIMC + part * 32;
            const float* fp = feat + (size_t)gr * DIMC + part * 32;
#pragma unroll
            for (int i = 0; i < 8; i++) {
                float4 hv = *(const float4*)(hp + i * 4);
                float4 fv = *(const float4*)(fp + i * 4);
                vals[i * 4 + 0] = hv.x + fv.x;
                vals[i * 4 + 1] = hv.y + fv.y;
                vals[i * 4 + 2] = hv.z + fv.z;
                vals[i * 4 + 3] = hv.w + fv.w;
            }
        } else {
#pragma unroll
            for (int i = 0; i < 32; i++) vals[i] = 0.0f;
        }
        float s = 0.0f;
#pragma unroll
        for (int i = 0; i < 32; i++) s += vals[i];
        s += __shfl_xor(s, 1); s += __shfl_xor(s, 2);
        float mu = s * (1.0f / 128.0f);
        float sq = 0.0f;
#pragma unroll
        for (int i = 0; i < 32; i++) { float d = vals[i] - mu; sq += d * d; }
        sq += __shfl_xor(sq, 1); sq += __shfl_xor(sq, 2);
        float rstd = 1.0f / sqrtf(sq * (1.0f / 128.0f) + 1e-5f);
#pragma unroll
        for (int i = 0; i < 32; i++) {
            int c = part * 32 + i;
            float yv = (vals[i] - mu) * rstd * g2[c] + b2[c];
            y_t[c][row] = (gr < NN) ? yv : 0.0f;
        }
    }
    __syncthreads();

    int tr = t >> 4, tc = t & 15;     // phase A: rows tr*4.., cols tc*2..; phase B: cols tc*8..
    float accO[4][8];
#pragma unroll
    for (int i = 0; i < 4; i++)
#pragma unroll
        for (int j = 0; j < 8; j++) accO[i][j] = 0.0f;

    for (int cc = 0; cc < 16; cc++) {
#pragma unroll
        for (int i = 0; i < 16; i++) {                 // stage W1 chunk [128][32]
            int e = t + i * 256;
            int k = e >> 5, c = e & 31;
            wbuf[k * 32 + c] = W1[(size_t)k * 512 + cc * 32 + c];
        }
        __syncthreads();
        float accA[4][2];
#pragma unroll
        for (int i = 0; i < 4; i++) { accA[i][0] = 0.0f; accA[i][1] = 0.0f; }
#pragma unroll 4
        for (int k = 0; k < 128; k++) {
            float4 a  = *(const float4*)&y_t[k][tr * 4];
            float  b0 = wbuf[k * 32 + tc * 2];
            float  b1 = wbuf[k * 32 + tc * 2 + 1];
            accA[0][0] = fmaf(a.x, b0, accA[0][0]); accA[0][1] = fmaf(a.x, b1, accA[0][1]);
            accA[1][0] = fmaf(a.y, b0, accA[1][0]); accA[1][1] = fmaf(a.y, b1, accA[1][1]);
            accA[2][0] = fmaf(a.z, b0, accA[2][0]); accA[2][1] = fmaf(a.z, b1, accA[2][1]);
            accA[3][0] = fmaf(a.w, b0, accA[3][0]); accA[3][1] = fmaf(a.w, b1, accA[3][1]);
        }
#pragma unroll
        for (int i = 0; i < 4; i++)
#pragma unroll
            for (int j = 0; j < 2; j++) {
                float v = accA[i][j] + bf1[cc * 32 + tc * 2 + j];
                ts[tr * 4 + i][tc * 2 + j] = fmaxf(v, 0.0f);
            }
        __syncthreads();                                // ts done; wbuf reads done
#pragma unroll
        for (int i = 0; i < 16; i++) {                 // stage W2 chunk [32][128]
            int e = t + i * 256;
            int k = e >> 7, c = e & 127;
            wbuf[k * 128 + c] = W2[(size_t)(cc * 32 + k) * 128 + c];
        }
        __syncthreads();
#pragma unroll 4
        for (int k = 0; k < 32; k++) {
            float a0 = ts[tr * 4 + 0][k];
            float a1 = ts[tr * 4 + 1][k];
            float a2 = ts[tr * 4 + 2][k];
            float a3 = ts[tr * 4 + 3][k];
            float4 b0 = *(const float4*)&wbuf[k * 128 + tc * 8];
            float4 b1 = *(const float4*)&wbuf[k * 128 + tc * 8 + 4];
            float bv[8] = {b0.x, b0.y, b0.z, b0.w, b1.x, b1.y, b1.z, b1.w};
#pragma unroll
            for (int j = 0; j < 8; j++) {
                accO[0][j] = fmaf(a0, bv[j], accO[0][j]);
                accO[1][j] = fmaf(a1, bv[j], accO[1][j]);
                accO[2][j] = fmaf(a2, bv[j], accO[2][j]);
                accO[3][j] = fmaf(a3, bv[j], accO[3][j]);
            }
        }
        __syncthreads();                                // before next chunk overwrites wbuf/ts
    }
    // epilogue: + b_ff2 + rst
#pragma unroll
    for (int i = 0; i < 4; i++) {
        int gr = r0 + tr * 4 + i;
        if (gr < NN) {
#pragma unroll
            for (int j = 0; j < 8; j++) {
                int c = tc * 8 + j;
                float rst = hfin[(size_t)gr * DIMC + c] + feat[(size_t)gr * DIMC + c];
                out[(size_t)gr * DIMC + c] = accO[i][j] + bf2[c] + rst;
            }
        }
    }
}

extern "C" void kernel_launch(void* const* d_in, const int* in_sizes, int n_in,
                              void* d_out, int out_size, void* d_ws, size_t ws_size,
                              hipStream_t stream) {
    const float* feat = (const float*)d_in[0];
    const float* Wh   = (const float*)d_in[1];
    const float* Wt   = (const float*)d_in[2];
    const float* We   = (const float*)d_in[3];
    const float* attn = (const float*)d_in[4];
    const float* g1   = (const float*)d_in[5];
    const float* b1   = (const float*)d_in[6];
    const float* g2   = (const float*)d_in[7];
    const float* b2   = (const float*)d_in[8];
    const float* W1   = (const float*)d_in[9];
    const float* bf1  = (const float*)d_in[10];
    const float* W2   = (const float*)d_in[11];
    const float* bf2  = (const float*)d_in[12];
    const int*   src  = (const int*)d_in[13];
    float* out = (float*)d_out;

    float* ws = (float*)d_ws;
    size_t NM = (size_t)NN * DIMC;
    float* x  = ws;
    float* fh = ws + NM;
    float* ft = ws + 2 * NM;
    float* fe = ws + 3 * NM;
    float* an = x;   // x dead after k_gemm3; reuse for a_n

    k_ln1<<<NN / 4, 256, 0, stream>>>(feat, g1, b1, x);

    dim3 gg((NN + 63) / 64, 3);
    k_gemm3<<<gg, 128, 0, stream>>>(x, Wh, Wt, We, fh, ft, fe);

    k_score<<<(NN * HC + 255) / 256, 256, 0, stream>>>(fh, ft, attn, src, an);

    // 5 hops, ping-pong through fh/ft (dead after k_score); fe preserved
    const float* hin = fe;
    for (int hop = 0; hop < 5; hop++) {
        float* hout = (hop % 2 == 0) ? fh : ft;
        k_hop<<<NN / 2, 256, 0, stream>>>(hin, fe, an, src, hout);
        hin = hout;
    }
    // after 5 hops, final h is in fh
    k_final<<<(NN + 63) / 64, 256, 0, stream>>>(hin, feat, g2, b2, W1, bf1, W2, bf2, out);
}

// Round 4
// 596.994 us; speedup vs baseline: 1.7317x; 1.7317x over previous
//
#include <hip/hip_runtime.h>
#include <cmath>

#define NN   50000
#define DIMC 128
#define HC   8
#define HDC  16
#define DC   16

typedef __bf16 bf16x8 __attribute__((ext_vector_type(8)));
typedef float  f32x4  __attribute__((ext_vector_type(4)));

__device__ __forceinline__ unsigned short f2bf(float f) {
    unsigned int x = __float_as_uint(f);
    unsigned int r = x + 0x7fffu + ((x >> 16) & 1u);
    return (unsigned short)(r >> 16);
}
__device__ __forceinline__ float bf2f(unsigned short u) {
    return __uint_as_float(((unsigned int)u) << 16);
}
// pair-granular (16B) XOR swizzle for [R][128] ushort LDS arrays
__device__ __forceinline__ int swz128(int r, int c) {
    return r * 128 + ((((c >> 3) ^ (r & 7)) << 3) | (c & 7));
}
__device__ __forceinline__ bf16x8 ldfrag(const unsigned short* lds, int off_lo, int off_hi) {
    union { uint2 u[2]; bf16x8 v; } t;
    t.u[0] = *(const uint2*)(lds + off_lo);
    t.u[1] = *(const uint2*)(lds + off_hi);
    return t.v;
}

// ---------------- LayerNorm #1: x = LN(feat)*g1 + b1 ----------------
__global__ __launch_bounds__(256) void k_ln1(const float* __restrict__ in,
                                             const float* __restrict__ g,
                                             const float* __restrict__ b,
                                             float* __restrict__ out) {
    int wid  = threadIdx.x >> 6;
    int lane = threadIdx.x & 63;
    int row  = blockIdx.x * 4 + wid;
    if (row >= NN) return;
    const float* rp = in + (size_t)row * DIMC;
    float2 v = *(const float2*)(rp + lane * 2);
    float s = v.x + v.y;
#pragma unroll
    for (int off = 32; off; off >>= 1) s += __shfl_xor(s, off);
    float mu = s * (1.0f / DIMC);
    float dx = v.x - mu, dy = v.y - mu;
    float sq = dx * dx + dy * dy;
#pragma unroll
    for (int off = 32; off; off >>= 1) sq += __shfl_xor(sq, off);
    float var  = sq * (1.0f / DIMC);
    float rstd = 1.0f / sqrtf(var + 1e-5f);
    float2 gv = *(const float2*)(g + lane * 2);
    float2 bv = *(const float2*)(b + lane * 2);
    float2 o;
    o.x = dx * rstd * gv.x + bv.x;
    o.y = dy * rstd * gv.y + bv.y;
    *(float2*)(out + (size_t)row * DIMC + lane * 2) = o;
}

// ---------------- one-time: transpose + bf16-convert FFN weights ----------------
__global__ __launch_bounds__(256) void k_cvtw(const float* __restrict__ W1,
                                              const float* __restrict__ W2,
                                              unsigned short* __restrict__ W1T,   // [512][128]
                                              unsigned short* __restrict__ W2T) { // [128][512]
    int i = blockIdx.x * 256 + threadIdx.x;   // 0..65535
    {
        int c = i >> 7, k = i & 127;
        W1T[i] = f2bf(W1[(size_t)k * 512 + c]);
    }
    {
        int o = i >> 9, c = i & 511;
        W2T[i] = f2bf(W2[(size_t)c * 128 + o]);
    }
}

// ---------------- 3x GEMM: C = x @ W (fp32 vector; score path untouched) --------
__global__ __launch_bounds__(128) void k_gemm3(const float* __restrict__ A,
                                               const float* __restrict__ B0,
                                               const float* __restrict__ B1,
                                               const float* __restrict__ B2,
                                               float* __restrict__ C0,
                                               float* __restrict__ C1,
                                               unsigned short* __restrict__ C2bf) {
    const float* B = (blockIdx.y == 0) ? B0 : (blockIdx.y == 1 ? B1 : B2);
    float*       C = (blockIdx.y == 0) ? C0 : C1;
    __shared__ __align__(16) float As[32][68];
    __shared__ __align__(16) float Bs[32][128];
    int t  = threadIdx.x;
    int tr = t >> 4, tc = t & 15;
    int r0 = blockIdx.x * 64;

    float acc[8][8];
#pragma unroll
    for (int i = 0; i < 8; i++)
#pragma unroll
        for (int j = 0; j < 8; j++) acc[i][j] = 0.0f;

    for (int kc = 0; kc < 4; kc++) {
#pragma unroll
        for (int i = 0; i < 16; i++) {
            int e = t + i * 128;
            int row = e >> 5, kk = e & 31;
            int gr = r0 + row;
            float v = (gr < NN) ? A[(size_t)gr * DIMC + kc * 32 + kk] : 0.0f;
            As[kk][row] = v;
        }
#pragma unroll
        for (int i = 0; i < 32; i++) {
            int e = t + i * 128;
            int kk = e >> 7, c = e & 127;
            Bs[kk][c] = B[(size_t)(kc * 32 + kk) * DIMC + c];
        }
        __syncthreads();
#pragma unroll 4
        for (int kk = 0; kk < 32; kk++) {
            float4 a0 = *(const float4*)&As[kk][tr * 8];
            float4 a1 = *(const float4*)&As[kk][tr * 8 + 4];
            float4 b0 = *(const float4*)&Bs[kk][tc * 8];
            float4 b1 = *(const float4*)&Bs[kk][tc * 8 + 4];
            float av[8] = {a0.x, a0.y, a0.z, a0.w, a1.x, a1.y, a1.z, a1.w};
            float bv[8] = {b0.x, b0.y, b0.z, b0.w, b1.x, b1.y, b1.z, b1.w};
#pragma unroll
            for (int i = 0; i < 8; i++)
#pragma unroll
                for (int j = 0; j < 8; j++) acc[i][j] = fmaf(av[i], bv[j], acc[i][j]);
        }
        __syncthreads();
    }
#pragma unroll
    for (int i = 0; i < 8; i++) {
        int gr = r0 + tr * 8 + i;
        if (gr < NN) {
            if (blockIdx.y < 2) {
                float4 o0 = {acc[i][0], acc[i][1], acc[i][2], acc[i][3]};
                float4 o1 = {acc[i][4], acc[i][5], acc[i][6], acc[i][7]};
                *(float4*)&C[(size_t)gr * DIMC + tc * 8]     = o0;
                *(float4*)&C[(size_t)gr * DIMC + tc * 8 + 4] = o1;
            } else {
                uint4 pk;
                pk.x = (unsigned int)f2bf(acc[i][0]) | ((unsigned int)f2bf(acc[i][1]) << 16);
                pk.y = (unsigned int)f2bf(acc[i][2]) | ((unsigned int)f2bf(acc[i][3]) << 16);
                pk.z = (unsigned int)f2bf(acc[i][4]) | ((unsigned int)f2bf(acc[i][5]) << 16);
                pk.w = (unsigned int)f2bf(acc[i][6]) | ((unsigned int)f2bf(acc[i][7]) << 16);
                *(uint4*)&C2bf[(size_t)gr * DIMC + tc * 8] = pk;
            }
        }
    }
}

// ---------------- scores -> softmax -> top-5 -> compact (w, idx) lists ----------
__global__ __launch_bounds__(256) void k_score(const float* __restrict__ fh,
                                               const float* __restrict__ ft,
                                               const float* __restrict__ attn,
                                               const int* __restrict__ src,
                                               float* __restrict__ w8,
                                               int* __restrict__ i8) {
    int idx = blockIdx.x * 256 + threadIdx.x;
    if (idx >= NN * HC) return;
    int n = idx >> 3, h = idx & 7;

    float ftv[16], atv[16];
    const float* ftp = ft + (size_t)n * DIMC + h * HDC;
    const float* atp = attn + h * HDC;
#pragma unroll
    for (int q = 0; q < 4; q++) {
        float4 a = *(const float4*)(ftp + q * 4);
        float4 b = *(const float4*)(atp + q * 4);
        ftv[q * 4 + 0] = a.x; ftv[q * 4 + 1] = a.y; ftv[q * 4 + 2] = a.z; ftv[q * 4 + 3] = a.w;
        atv[q * 4 + 0] = b.x; atv[q * 4 + 1] = b.y; atv[q * 4 + 2] = b.z; atv[q * 4 + 3] = b.w;
    }
    const int* sp = src + (size_t)n * DC;
    const float scale = logf(17.0f) / 16.0f;
    float sc[16];
#pragma unroll
    for (int d = 0; d < 16; d++) {
        int r = sp[d];
        const float* fp = fh + (size_t)r * DIMC + h * HDC;
        float s = 0.0f;
#pragma unroll
        for (int q = 0; q < 4; q++) {
            float4 v = *(const float4*)(fp + q * 4);
            float e;
            e = v.x + ftv[q * 4 + 0]; e = e > 0.0f ? e : 0.2f * e; s = fmaf(atv[q * 4 + 0], e, s);
            e = v.y + ftv[q * 4 + 1]; e = e > 0.0f ? e : 0.2f * e; s = fmaf(atv[q * 4 + 1], e, s);
            e = v.z + ftv[q * 4 + 2]; e = e > 0.0f ? e : 0.2f * e; s = fmaf(atv[q * 4 + 2], e, s);
            e = v.w + ftv[q * 4 + 3]; e = e > 0.0f ? e : 0.2f * e; s = fmaf(atv[q * 4 + 3], e, s);
        }
        sc[d] = s * scale;
    }
    float m = sc[0];
#pragma unroll
    for (int d = 1; d < 16; d++) m = fmaxf(m, sc[d]);
    float p[16]; float sum = 0.0f;
#pragma unroll
    for (int d = 0; d < 16; d++) { p[d] = expf(sc[d] - m); sum += p[d]; }
    float a[16];
#pragma unroll
    for (int d = 0; d < 16; d++) a[d] = p[d] / sum;
    float tmp[16];
#pragma unroll
    for (int d = 0; d < 16; d++) tmp[d] = a[d];
    float thr = 0.0f;
#pragma unroll
    for (int k = 0; k < 5; k++) {
        float vm = tmp[0];
#pragma unroll
        for (int d = 1; d < 16; d++) vm = fmaxf(vm, tmp[d]);
        thr = vm;
        bool rem = false;
#pragma unroll
        for (int d = 0; d < 16; d++) {
            if (!rem && tmp[d] == vm) { tmp[d] = -1.0f; rem = true; }
        }
    }
    float tsum = 0.0f;
#pragma unroll
    for (int d = 0; d < 16; d++) if (a[d] >= thr) tsum += a[d];

    float wv[8]; int iv[8];
    int s = 0;
#pragma unroll
    for (int d = 0; d < 16; d++) {
        if (a[d] >= thr && s < 8) { wv[s] = a[d] / tsum; iv[s] = sp[d]; s++; }
    }
    for (; s < 8; s++) { wv[s] = 0.0f; iv[s] = 0; }
    size_t base = ((size_t)n * HC + h) * 8;
    float4 w0 = {wv[0], wv[1], wv[2], wv[3]};
    float4 w1 = {wv[4], wv[5], wv[6], wv[7]};
    *(float4*)&w8[base]     = w0;
    *(float4*)&w8[base + 4] = w1;
    int4 i0 = {iv[0], iv[1], iv[2], iv[3]};
    int4 i1 = {iv[4], iv[5], iv[6], iv[7]};
    *(int4*)&i8[base]     = i0;
    *(int4*)&i8[base + 4] = i1;
}

// ---------------- one propagation hop (bf16 h) ----------------
__global__ __launch_bounds__(256) void k_hop(const unsigned short* __restrict__ hin,
                                             const unsigned short* __restrict__ febf,
                                             const float* __restrict__ w8,
                                             const int* __restrict__ i8,
                                             unsigned short* __restrict__ hout) {
    __shared__ float s_w[256];
    __shared__ int   s_i[256];
    int t  = threadIdx.x;
    int n0 = blockIdx.x * 4;               // 4 nodes / block
    s_w[t] = w8[(size_t)n0 * 64 + t];
    s_i[t] = i8[(size_t)n0 * 64 + t];
    __syncthreads();
    int g = t >> 3, lane = t & 7;          // group = (node, head); 8 lanes = 16 feats
    int n = n0 + (g >> 3);
    int h = g & 7;
    const unsigned int* hin32 = (const unsigned int*)hin;
    float a0 = 0.0f, a1 = 0.0f;
    int base = g * 8;
#pragma unroll
    for (int j = 0; j < 8; j++) {
        float wv = s_w[base + j];
        if (wv != 0.0f) {
            int r = s_i[base + j];
            unsigned int u = hin32[(size_t)r * 64 + h * 8 + lane];
            a0 = fmaf(wv, __uint_as_float(u << 16), a0);
            a1 = fmaf(wv, __uint_as_float(u & 0xffff0000u), a1);
        }
    }
    unsigned int fu = ((const unsigned int*)febf)[(size_t)n * 64 + h * 8 + lane];
    a0 = 0.9f * a0 + 0.1f * __uint_as_float(fu << 16);
    a1 = 0.9f * a1 + 0.1f * __uint_as_float(fu & 0xffff0000u);
    ((unsigned int*)hout)[(size_t)n * 64 + h * 8 + lane] =
        (unsigned int)f2bf(a0) | ((unsigned int)f2bf(a1) << 16);
}

// ---------------- rst + LN2 + FFN (bf16 MFMA) + residual ----------------
__global__ __launch_bounds__(256) void k_final(
        const unsigned short* __restrict__ hb,   // h after 5 hops, bf16 [NN][128]
        const float* __restrict__ feat,
        const float* __restrict__ g2,
        const float* __restrict__ b2,
        const unsigned short* __restrict__ W1T,  // [512][128] bf16
        const float* __restrict__ bf1,
        const unsigned short* __restrict__ W2T,  // [128][512] bf16
        const float* __restrict__ bf2,
        float* __restrict__ out) {
    __shared__ unsigned short yrm[64 * 128];   // y bf16 [m][k], swizzled
    __shared__ unsigned short wbuf[128 * 128]; // W1T / W2T chunk, swizzled
    __shared__ unsigned short Trm[64 * 128];   // relu(t) bf16 [m][c], swizzled
    __shared__ float sbf1[512];
    __shared__ float sg2[128];
    __shared__ float sb2[128];
    int t  = threadIdx.x;
    int r0 = blockIdx.x * 64;

    sbf1[t]       = bf1[t];
    sbf1[t + 256] = bf1[t + 256];
    if (t < 128) { sg2[t] = g2[t]; sb2[t] = b2[t]; }
    __syncthreads();

    // ---- rst = bf2f(h)+feat; LN2 -> y bf16 into yrm ----
    {
        int row = t >> 2, part = t & 3;
        int gr = r0 + row;
        float vals[32];
        if (gr < NN) {
            const unsigned short* hp = hb + (size_t)gr * DIMC + part * 32;
            const float* fp = feat + (size_t)gr * DIMC + part * 32;
#pragma unroll
            for (int i = 0; i < 4; i++) {
                uint4 hv = *(const uint4*)(hp + i * 8);
                float4 f0 = *(const float4*)(fp + i * 8);
                float4 f1 = *(const float4*)(fp + i * 8 + 4);
                vals[i*8+0] = __uint_as_float(hv.x << 16)          + f0.x;
                vals[i*8+1] = __uint_as_float(hv.x & 0xffff0000u)  + f0.y;
                vals[i*8+2] = __uint_as_float(hv.y << 16)          + f0.z;
                vals[i*8+3] = __uint_as_float(hv.y & 0xffff0000u)  + f0.w;
                vals[i*8+4] = __uint_as_float(hv.z << 16)          + f1.x;
                vals[i*8+5] = __uint_as_float(hv.z & 0xffff0000u)  + f1.y;
                vals[i*8+6] = __uint_as_float(hv.w << 16)          + f1.z;
                vals[i*8+7] = __uint_as_float(hv.w & 0xffff0000u)  + f1.w;
            }
        } else {
#pragma unroll
            for (int i = 0; i < 32; i++) vals[i] = 0.0f;
        }
        float s = 0.0f;
#pragma unroll
        for (int i = 0; i < 32; i++) s += vals[i];
        s += __shfl_xor(s, 1); s += __shfl_xor(s, 2);
        float mu = s * (1.0f / 128.0f);
        float sq = 0.0f;
#pragma unroll
        for (int i = 0; i < 32; i++) { float d = vals[i] - mu; sq += d * d; }
        sq += __shfl_xor(sq, 1); sq += __shfl_xor(sq, 2);
        float rstd = 1.0f / sqrtf(sq * (1.0f / 128.0f) + 1e-5f);
#pragma unroll
        for (int pp = 0; pp < 4; pp++) {
            int c = part * 32 + pp * 8;
            unsigned int pk[4];
#pragma unroll
            for (int e = 0; e < 8; e += 2) {
                float y0 = (gr < NN) ? ((vals[pp*8+e]   - mu) * rstd * sg2[c+e]   + sb2[c+e])   : 0.0f;
                float y1 = (gr < NN) ? ((vals[pp*8+e+1] - mu) * rstd * sg2[c+e+1] + sb2[c+e+1]) : 0.0f;
                pk[e >> 1] = (unsigned int)f2bf(y0) | ((unsigned int)f2bf(y1) << 16);
            }
            uint4 v = {pk[0], pk[1], pk[2], pk[3]};
            *(uint4*)&yrm[swz128(row, c)] = v;
        }
    }

    int w  = t >> 6;
    int l  = t & 63;
    int lr = l & 15;
    int lg = l >> 4;
    f32x4 zero4 = {0.0f, 0.0f, 0.0f, 0.0f};
    f32x4 accO[4][2];
#pragma unroll
    for (int mt = 0; mt < 4; mt++)
#pragma unroll
        for (int ot = 0; ot < 2; ot++) accO[mt][ot] = zero4;

    __syncthreads();

    for (int cc = 0; cc < 4; cc++) {
        // stage W1T chunk [128 c][128 k]
#pragma unroll
        for (int i = 0; i < 8; i++) {
            int q = i * 256 + t;
            int c = q >> 4, p = q & 15;
            uint4 v = *(const uint4*)(W1T + (((size_t)(cc * 128 + c)) << 7) + p * 8);
            *(uint4*)&wbuf[swz128(c, p * 8)] = v;
        }
        __syncthreads();

        // phase A: Tt[c][m] = W1cT @ yT   (wave w owns c in [w*32, w*32+32))
        f32x4 tacc[2][4];
#pragma unroll
        for (int ct = 0; ct < 2; ct++)
#pragma unroll
            for (int mt = 0; mt < 4; mt++) tacc[ct][mt] = zero4;
        int cb = w * 32;
#pragma unroll
        for (int kf = 0; kf < 4; kf++) {
            int k0 = kf * 32;
            bf16x8 af[2], bfr[4];
#pragma unroll
            for (int ct = 0; ct < 2; ct++) {
                int c = cb + ct * 16 + lr;
                af[ct] = ldfrag(wbuf, swz128(c, k0 + lg * 4), swz128(c, k0 + 16 + lg * 4));
            }
#pragma unroll
            for (int mt = 0; mt < 4; mt++) {
                int m = mt * 16 + lr;
                bfr[mt] = ldfrag(yrm, swz128(m, k0 + lg * 4), swz128(m, k0 + 16 + lg * 4));
            }
#pragma unroll
            for (int ct = 0; ct < 2; ct++)
#pragma unroll
                for (int mt = 0; mt < 4; mt++)
                    tacc[ct][mt] = __builtin_amdgcn_mfma_f32_16x16x32_bf16(af[ct], bfr[mt], tacc[ct][mt], 0, 0, 0);
        }
        // bias + relu + cvt -> Trm[m][c]
#pragma unroll
        for (int ct = 0; ct < 2; ct++)
#pragma unroll
            for (int mt = 0; mt < 4; mt++) {
                int c0 = cb + ct * 16 + lg * 4;
                int m  = mt * 16 + lr;
                float v0 = fmaxf(tacc[ct][mt][0] + sbf1[cc * 128 + c0 + 0], 0.0f);
                float v1 = fmaxf(tacc[ct][mt][1] + sbf1[cc * 128 + c0 + 1], 0.0f);
                float v2 = fmaxf(tacc[ct][mt][2] + sbf1[cc * 128 + c0 + 2], 0.0f);
                float v3 = fmaxf(tacc[ct][mt][3] + sbf1[cc * 128 + c0 + 3], 0.0f);
                unsigned int lo = (unsigned int)f2bf(v0) | ((unsigned int)f2bf(v1) << 16);
                unsigned int hi = (unsigned int)f2bf(v2) | ((unsigned int)f2bf(v3) << 16);
                uint2 pv = {lo, hi};
                *(uint2*)&Trm[swz128(m, c0)] = pv;
            }
        __syncthreads();
        // stage W2T chunk [128 o][128 c]
#pragma unroll
        for (int i = 0; i < 8; i++) {
            int q = i * 256 + t;
            int o = q >> 4, p = q & 15;
            uint4 v = *(const uint4*)(W2T + ((size_t)o << 9) + cc * 128 + p * 8);
            *(uint4*)&wbuf[swz128(o, p * 8)] = v;
        }
        __syncthreads();
        // phase B: out[m][o] += Trm @ W2cT   (wave w owns o in [w*32, w*32+32))
        int ob = w * 32;
#pragma unroll
        for (int kf = 0; kf < 4; kf++) {
            int k0 = kf * 32;
            bf16x8 aT[4], bw[2];
#pragma unroll
            for (int mt = 0; mt < 4; mt++) {
                int m = mt * 16 + lr;
                aT[mt] = ldfrag(Trm, swz128(m, k0 + lg * 4), swz128(m, k0 + 16 + lg * 4));
            }
#pragma unroll
            for (int ot = 0; ot < 2; ot++) {
                int o = ob + ot * 16 + lr;
                bw[ot] = ldfrag(wbuf, swz128(o, k0 + lg * 4), swz128(o, k0 + 16 + lg * 4));
            }
#pragma unroll
            for (int mt = 0; mt < 4; mt++)
#pragma unroll
                for (int ot = 0; ot < 2; ot++)
                    accO[mt][ot] = __builtin_amdgcn_mfma_f32_16x16x32_bf16(aT[mt], bw[ot], accO[mt][ot], 0, 0, 0);
        }
        __syncthreads();
    }
    // epilogue: + bf2 + rst
    int ob = w * 32;
#pragma unroll
    for (int mt = 0; mt < 4; mt++) {
#pragma unroll
        for (int j = 0; j < 4; j++) {
            int m = mt * 16 + lg * 4 + j;
            int gr = r0 + m;
            if (gr < NN) {
#pragma unroll
                for (int ot = 0; ot < 2; ot++) {
                    int o = ob + ot * 16 + lr;
                    float rst = bf2f(hb[(size_t)gr * DIMC + o]) + feat[(size_t)gr * DIMC + o];
                    out[(size_t)gr * DIMC + o] = accO[mt][ot][j] + bf2[o] + rst;
                }
            }
        }
    }
}

extern "C" void kernel_launch(void* const* d_in, const int* in_sizes, int n_in,
                              void* d_out, int out_size, void* d_ws, size_t ws_size,
                              hipStream_t stream) {
    const float* feat = (const float*)d_in[0];
    const float* Wh   = (const float*)d_in[1];
    const float* Wt   = (const float*)d_in[2];
    const float* We   = (const float*)d_in[3];
    const float* attn = (const float*)d_in[4];
    const float* g1   = (const float*)d_in[5];
    const float* b1   = (const float*)d_in[6];
    const float* g2   = (const float*)d_in[7];
    const float* b2   = (const float*)d_in[8];
    const float* W1   = (const float*)d_in[9];
    const float* bf1  = (const float*)d_in[10];
    const float* W2   = (const float*)d_in[11];
    const float* bf2  = (const float*)d_in[12];
    const int*   src  = (const int*)d_in[13];
    float* out = (float*)d_out;

    float* ws_f = (float*)d_ws;
    size_t NM = (size_t)NN * DIMC;                    // 6.4M
    float* x  = ws_f;                                 // [NM]   LN out -> later w8/i8
    float* fh = ws_f + NM;                            // [NM]   fh    -> later hb0/hb1
    float* ft = ws_f + 2 * NM;                        // [NM]
    unsigned short* febf = (unsigned short*)(ws_f + 3 * NM);  // [NM] bf16
    unsigned short* W1Tb = febf + NM;                 // [512*128]
    unsigned short* W2Tb = W1Tb + 65536;              // [128*512]
    float* w8 = x;                                    // [NN*64]
    int*   i8 = (int*)(x + (size_t)NN * 64);          // [NN*64]
    unsigned short* hb0 = (unsigned short*)fh;        // [NM] bf16
    unsigned short* hb1 = hb0 + NM;                   // [NM] bf16

    k_cvtw<<<256, 256, 0, stream>>>(W1, W2, W1Tb, W2Tb);
    k_ln1<<<NN / 4, 256, 0, stream>>>(feat, g1, b1, x);

    dim3 gg((NN + 63) / 64, 3);
    k_gemm3<<<gg, 128, 0, stream>>>(x, Wh, Wt, We, fh, ft, febf);

    k_score<<<(NN * HC + 255) / 256, 256, 0, stream>>>(fh, ft, attn, src, w8, i8);

    const unsigned short* hin = febf;
    for (int hop = 0; hop < 5; hop++) {
        unsigned short* hout = (hop % 2 == 0) ? hb0 : hb1;
        k_hop<<<NN / 4, 256, 0, stream>>>(hin, febf, w8, i8, hout);
        hin = hout;
    }
    // final h in hb0
    k_final<<<(NN + 63) / 64, 256, 0, stream>>>(hb0, feat, g2, b2, W1Tb, bf1, W2Tb, bf2, out);
}